// Round 3
// baseline (239.348 us; speedup 1.0000x reference)
//
#include <hip/hip_runtime.h>
#include <hip/hip_bf16.h>

// LengthRegulator fused: B=32, T=512, C=384, MAX_LEN=4096 (fixed shapes).
// out[b,p,:] = x[b, t(p), :], t(p) = #{j : csum[b,j] <= p} (clip T-1),
// zero for p >= mel_len[b] = csum[b,T-1]; mel_len appended as float32.
// Single kernel: each block re-computes its batch's 512-elem prefix sum
// (cheap, parallel) then streams its 128-position tile with NT stores.

#define B   32
#define T   512
#define C   384
#define C4  96          // C / 4
#define ML  4096
#define PPB 128         // positions per block
#define TPB 256         // threads per block

typedef float v4f __attribute__((ext_vector_type(4)));   // clang vector: OK for NT builtins

__global__ __launch_bounds__(TPB)
void lr_fused_kernel(const float* __restrict__ x,
                     const int* __restrict__ dur,
                     float* __restrict__ out,
                     float* __restrict__ mel_out) {
    __shared__ int s_cs[T];
    __shared__ int s_p[TPB];
    __shared__ int s_idx[PPB];

    const int tilesPerBatch = ML / PPB;            // 32
    const int b     = blockIdx.x / tilesPerBatch;
    const int ptile = blockIdx.x % tilesPerBatch;
    const int tid   = threadIdx.x;

    // --- scan: 2 durations per thread, Hillis-Steele over 256 pair-sums ---
    int2 d2 = ((const int2*)(dur + b * T))[tid];
    int d0 = d2.x < 0 ? 0 : d2.x;
    int d1 = d2.y < 0 ? 0 : d2.y;
    s_p[tid] = d0 + d1;
    __syncthreads();
    #pragma unroll
    for (int off = 1; off < TPB; off <<= 1) {
        int add = (tid >= off) ? s_p[tid - off] : 0;
        __syncthreads();
        s_p[tid] += add;
        __syncthreads();
    }
    const int S = s_p[tid];                        // inclusive through elem 2t+1
    s_cs[2 * tid + 1] = S;
    s_cs[2 * tid]     = S - d1;
    __syncthreads();

    const int mel = s_cs[T - 1];
    if (ptile == 0 && tid == 0) mel_out[b] = (float)mel;

    // --- one binary search per position in this tile ---
    if (tid < PPB) {
        const int p = ptile * PPB + tid;
        int r = -1;                                // -1 => zero-fill
        if (p < mel) {
            int lo = 0, hi = T;                    // first index with cs[i] > p
            while (lo < hi) {
                int mid = (lo + hi) >> 1;
                if (s_cs[mid] <= p) lo = mid + 1; else hi = mid;
            }
            r = lo < (T - 1) ? lo : (T - 1);
        }
        s_idx[tid] = r;
    }
    __syncthreads();

    // --- streaming copy: PPB*C4 = 12288 float4, coalesced, NT stores ---
    const v4f* __restrict__ x4 = (const v4f*)x;
    v4f* __restrict__ o4 = (v4f*)out;
    const size_t xbase = (size_t)b * T * C4;
    const size_t obase = (size_t)b * ML * C4 + (size_t)ptile * PPB * C4;
    const v4f zero = (v4f){0.f, 0.f, 0.f, 0.f};

    #pragma unroll 4
    for (int v = tid; v < PPB * C4; v += TPB) {
        const int pl = v / C4;                     // magic-mul div
        const int c4 = v - pl * C4;
        const int t  = s_idx[pl];
        v4f val = zero;
        if (t >= 0) val = x4[xbase + (size_t)t * C4 + c4];
        __builtin_nontemporal_store(val, &o4[obase + v]);
    }
}

extern "C" void kernel_launch(void* const* d_in, const int* in_sizes, int n_in,
                              void* d_out, int out_size, void* d_ws, size_t ws_size,
                              hipStream_t stream) {
    const float* x   = (const float*)d_in[0];
    const int*   dur = (const int*)d_in[1];
    // d_in[2] = max_len (fixed 4096 for this bench)

    float* out     = (float*)d_out;                // B*ML*C floats
    float* mel_out = out + (size_t)B * ML * C;     // 32 floats (tail)

    const int grid = B * (ML / PPB);               // 1024 blocks
    lr_fused_kernel<<<grid, TPB, 0, stream>>>(x, dur, out, mel_out);
}

// Round 4
// 225.470 us; speedup vs baseline: 1.0616x; 1.0616x over previous
//
#include <hip/hip_runtime.h>
#include <hip/hip_bf16.h>

// LengthRegulator fused: B=32, T=512, C=384, MAX_LEN=4096 (fixed shapes).
// out[b,p,:] = x[b, t(p), :], t(p) = #{j : csum[b,j] <= p} (clip T-1),
// zero for p >= mel_len[b] = csum[b,T-1]; mel_len appended as float32.
//
// TPB=384 = 4*96: each thread owns a fixed float4-column c4 = tid%96 and
// row-subslot sub = tid/96 -> inner loop has no div/mod, fully coalesced.
// Plain (cached) stores: out = 192 MiB < 256 MiB L3, let the cache absorb
// the stream (NT stores measured +11 us in R3 by forcing sync HBM drain).

#define B   32
#define T   512
#define C4  96          // C/4 = 384/4
#define ML  4096
#define PPB 128         // positions per block
#define TPB 384         // threads per block (6 waves)

typedef float v4f __attribute__((ext_vector_type(4)));

__global__ __launch_bounds__(TPB)
void lr_fused_kernel(const float* __restrict__ x,
                     const int* __restrict__ dur,
                     float* __restrict__ out,
                     float* __restrict__ mel_out) {
    __shared__ int s_cs[T];
    __shared__ int s_wsum[4];
    __shared__ int s_idx[PPB];

    const int b     = blockIdx.x >> 5;        // / (ML/PPB) = /32
    const int ptile = blockIdx.x & 31;
    const int tid   = threadIdx.x;
    const int lane  = tid & 63;

    // ---- scan: threads 0..255 hold 2 durations each; shuffle scan ----
    int pairsum = 0, d1 = 0;
    if (tid < 256) {
        int2 d2 = ((const int2*)(dur + b * T))[tid];
        int d0 = d2.x < 0 ? 0 : d2.x;
        d1     = d2.y < 0 ? 0 : d2.y;
        pairsum = d0 + d1;
    }
    int incl = pairsum;                        // intra-wave inclusive scan
    #pragma unroll
    for (int off = 1; off < 64; off <<= 1) {
        int n = __shfl_up(incl, off, 64);
        if (lane >= off) incl += n;
    }
    if (tid < 256 && lane == 63) s_wsum[tid >> 6] = incl;
    __syncthreads();
    if (tid < 256) {
        const int w = tid >> 6;
        int wp = 0;
        #pragma unroll
        for (int j = 0; j < 3; ++j) if (j < w) wp += s_wsum[j];
        const int S = incl + wp;               // inclusive csum through 2*tid+1
        s_cs[2 * tid + 1] = S;
        s_cs[2 * tid]     = S - d1;
    }
    __syncthreads();

    const int mel = s_cs[T - 1];
    if (ptile == 0 && tid == 0) mel_out[b] = (float)mel;

    // ---- one binary search per position in this tile ----
    if (tid < PPB) {
        const int p = ptile * PPB + tid;
        int r = -1;                            // -1 => zero-fill
        if (p < mel) {
            int lo = 0, hi = T;                // first index with cs[i] > p
            while (lo < hi) {
                int mid = (lo + hi) >> 1;
                if (s_cs[mid] <= p) lo = mid + 1; else hi = mid;
            }
            r = lo < (T - 1) ? lo : (T - 1);
        }
        s_idx[tid] = r;
    }
    __syncthreads();

    // ---- streaming copy: fixed column per thread, 32 iterations ----
    const v4f* __restrict__ x4 = (const v4f*)x;
    v4f* __restrict__ o4 = (v4f*)out;
    const int sub = tid / 96;                  // 0..3 (computed once)
    const int c4  = tid - sub * 96;            // fixed float4 column
    const size_t xbase = (size_t)b * T * C4 + c4;
    const size_t obase = (size_t)b * ML * C4 + (size_t)ptile * PPB * C4 + c4;
    const v4f zero = (v4f){0.f, 0.f, 0.f, 0.f};

    #pragma unroll 8
    for (int k = 0; k < PPB / 4; ++k) {
        const int pl = 4 * k + sub;
        const int t  = s_idx[pl];
        v4f val = zero;
        if (t >= 0) val = x4[xbase + (size_t)t * C4];
        o4[obase + (size_t)pl * C4] = val;
    }
}

extern "C" void kernel_launch(void* const* d_in, const int* in_sizes, int n_in,
                              void* d_out, int out_size, void* d_ws, size_t ws_size,
                              hipStream_t stream) {
    const float* x   = (const float*)d_in[0];
    const int*   dur = (const int*)d_in[1];
    // d_in[2] = max_len (fixed 4096 for this bench)

    float* out     = (float*)d_out;            // B*ML*C floats
    float* mel_out = out + (size_t)B * ML * C4 * 4;  // 32 floats (tail)

    const int grid = B * (ML / PPB);           // 1024 blocks
    lr_fused_kernel<<<grid, TPB, 0, stream>>>(x, dur, out, mel_out);
}